// Round 17
// baseline (201.917 us; speedup 1.0000x reference)
//
#include <hip/hip_runtime.h>
#include <hip/hip_bf16.h>

// Problem: B=16, N=1024, EMB=128, H=8, INNER=1024
// out = proj( attention( LN(x) @ Wqkv ) ) + b_proj,  fp32 in/out, bf16-tolerance.

typedef __attribute__((ext_vector_type(8))) short bf16x8;
typedef __attribute__((ext_vector_type(4))) float f32x4;
typedef __attribute__((ext_vector_type(4))) unsigned int u32x4;

__device__ __forceinline__ unsigned short f2bf(float f) {
  unsigned int u = __float_as_uint(f);
  u += 0x7FFF + ((u >> 16) & 1);   // round-nearest-even
  return (unsigned short)(u >> 16);
}

// async global->LDS, 16B per lane; LDS dest = wave-uniform base + lane*16
__device__ __forceinline__ void gll16(const void* g, void* l) {
  __builtin_amdgcn_global_load_lds((const __attribute__((address_space(1))) unsigned int*)g,
                                   (__attribute__((address_space(3))) unsigned int*)l, 16, 0, 0);
}

// ---------------- merged prep: LN (blocks 0..4095), wqkv cast-T (4096..4143),
// ---------------- wproj cast-T (4144..4151)
__global__ __launch_bounds__(256) void k_prep(const float* __restrict__ x,
                                              const float* __restrict__ gamma,
                                              const float* __restrict__ beta,
                                              const float* __restrict__ wqkv,
                                              const float* __restrict__ wproj,
                                              unsigned short* __restrict__ xb,
                                              unsigned short* __restrict__ wqkvT,
                                              unsigned short* __restrict__ wprojT) {
  __shared__ unsigned short T[17152];            // 128*134 shorts, reused per branch
  const int bid = blockIdx.x, tid = threadIdx.x;
  if (bid < 4096) {
    int row  = bid * 4 + (tid >> 6);
    int lane = tid & 63;
    float2 v = *reinterpret_cast<const float2*>(x + row * 128 + lane * 2);
    float s = v.x + v.y, ss = v.x * v.x + v.y * v.y;
#pragma unroll
    for (int m = 1; m < 64; m <<= 1) { s += __shfl_xor(s, m); ss += __shfl_xor(ss, m); }
    float mu   = s * (1.0f / 128.0f);
    float var  = ss * (1.0f / 128.0f) - mu * mu;
    float rstd = rsqrtf(var + 1e-5f);
    float2 g  = *reinterpret_cast<const float2*>(gamma + lane * 2);
    float2 be = *reinterpret_cast<const float2*>(beta + lane * 2);
    ushort2 o;
    o.x = f2bf((v.x - mu) * rstd * g.x + be.x);
    o.y = f2bf((v.y - mu) * rstd * g.y + be.y);
    *reinterpret_cast<ushort2*>(xb + row * 128 + lane * 2) = o;
  } else if (bid < 4144) {
    const int n0 = (bid - 4096) * 64;            // w_qkv [128][3072] -> [3072][128]
#pragma unroll
    for (int i = 0; i < 32; i++) {
      int idx = i * 256 + tid;
      int k = idx >> 6, c = idx & 63;
      T[k * 70 + c] = f2bf(wqkv[k * 3072 + n0 + c]);
    }
    __syncthreads();
#pragma unroll
    for (int i = 0; i < 32; i++) {
      int idx = i * 256 + tid;
      int n = idx >> 7, k = idx & 127;
      wqkvT[(n0 + n) * 128 + k] = T[k * 70 + n];
    }
  } else {
    const int k0 = (bid - 4144) * 128;           // w_proj [1024][128] -> [128][1024]
#pragma unroll
    for (int i = 0; i < 64; i++) {
      int idx = i * 256 + tid;
      int r = idx >> 7, c = idx & 127;
      T[r * 134 + c] = f2bf(wproj[(k0 + r) * 128 + c]);
    }
    __syncthreads();
#pragma unroll
    for (int i = 0; i < 64; i++) {
      int idx = i * 256 + tid;
      int c = idx >> 7, r = idx & 127;
      wprojT[c * 1024 + k0 + r] = T[r * 134 + c];
    }
  }
}

// ------------- QKV GEMM: [16384,128] @ [128,3072]; writes Q,K [B,H,N,D], Vt [B,H,D,N]
// (byte-identical to R14: M-tile 64, 48KB LDS, V seq-permuted per 32-key tile)
__global__ __launch_bounds__(256) void k_qkv(const unsigned short* __restrict__ xb,
                                             const unsigned short* __restrict__ wt,  // [3072][128]
                                             unsigned short* __restrict__ qb,
                                             unsigned short* __restrict__ kb,
                                             unsigned short* __restrict__ vtb) {
  __shared__ __align__(16) unsigned short SH[24576];   // 48KB
  unsigned short* Xs = SH;                        // [64][128]
  unsigned short* Ws = SH + 8192;                 // [128][128]
  const int m0 = blockIdx.x * 64;
  const int n0 = blockIdx.y * 128;
  const int tid = threadIdx.x, wave = tid >> 6, lane = tid & 63;
  const int lm = lane & 15, lg = lane >> 4;
  const int wr = wave >> 1, wc = wave & 1;

#pragma unroll
  for (int ii = 0; ii < 4; ii++) {                // X: 16 rows per wave
    int row = wave * 16 + ii * 4 + (lane >> 4);
    int c = (lane & 15) ^ (row & 7);
    gll16(xb + (m0 + row) * 128 + c * 8, Xs + (wave * 16 + ii * 4) * 128);
  }
#pragma unroll
  for (int ii = 0; ii < 8; ii++) {                // W: 32 rows per wave
    int row = wave * 32 + ii * 4 + (lane >> 4);
    int c = (lane & 15) ^ (row & 7);
    gll16(wt + (n0 + row) * 128 + c * 8, Ws + (wave * 32 + ii * 4) * 128);
  }
  __syncthreads();

  f32x4 acc[2][4];
#pragma unroll
  for (int i = 0; i < 2; i++)
#pragma unroll
    for (int j = 0; j < 4; j++) acc[i][j] = {0.f, 0.f, 0.f, 0.f};

#pragma unroll
  for (int k32 = 0; k32 < 4; k32++) {
    bf16x8 af[2], bfr[4];
#pragma unroll
    for (int mi = 0; mi < 2; mi++) {
      int row = wr * 32 + mi * 16 + lm;
      af[mi] = *(const bf16x8*)((const char*)(Xs + row * 128) + ((k32 * 64 + lg * 16) ^ ((lm & 7) << 4)));
    }
#pragma unroll
    for (int ni = 0; ni < 4; ni++) {
      int row = wc * 64 + ni * 16 + lm;
      bfr[ni] = *(const bf16x8*)((const char*)(Ws + row * 128) + ((k32 * 64 + lg * 16) ^ ((lm & 7) << 4)));
    }
#pragma unroll
    for (int mi = 0; mi < 2; mi++)
#pragma unroll
      for (int ni = 0; ni < 4; ni++)
        acc[mi][ni] = __builtin_amdgcn_mfma_f32_16x16x32_bf16(af[mi], bfr[ni], acc[mi][ni], 0, 0, 0);
  }

  // epilogue: repack through LDS for coalesced stores.
  __syncthreads();
  unsigned short* T = SH;
  const int isV = (n0 >= 2048);
  const float qscale = (n0 < 1024) ? 0.04508422f : 1.0f;
#pragma unroll
  for (int mi = 0; mi < 2; mi++)
#pragma unroll
    for (int ni = 0; ni < 4; ni++)
#pragma unroll
      for (int j = 0; j < 4; j++) {
        int mloc = wr * 32 + mi * 16 + 4 * lg + j;
        int nloc = wc * 64 + ni * 16 + lm;
        unsigned short v = f2bf(acc[mi][ni][j] * qscale);
        if (isV) T[nloc * 72 + mloc] = v;
        else     T[mloc * 136 + nloc] = v;
      }
  __syncthreads();
  const int bb = m0 >> 10, seq0 = m0 & 1023;
  const int hh = (n0 & 1023) >> 7;
  const int bh = bb * 8 + hh;
  if (!isV) {
    unsigned short* outp = (n0 < 1024) ? (qb + (bh * 1024 + seq0) * 128)
                                       : (kb + (bh * 1024 + seq0) * 128);
#pragma unroll
    for (int i = 0; i < 16; i++) {                // 64 rows x 128 cols
      int flat = i * 512 + tid * 2;
      int row = flat >> 7, c = flat & 127;
      ushort2 v2 = *(ushort2*)&T[row * 136 + c];
      *(ushort2*)(outp + row * 128 + c) = v2;
    }
  } else {
    unsigned short* outp = vtb + bh * 131072 + seq0;
#pragma unroll
    for (int i = 0; i < 16; i++) {                // 128 rows(d) x 64 cols(seq), permuted
      int flat = i * 512 + tid * 2;
      int row = flat >> 6, c = flat & 63;
      int k = c & 31;
      int p = ((k & 12) << 1) | ((k >> 4) << 2) | (k & 3);   // pi^-1(key)
      int cp = (c & 32) | p;
      ushort2 v2 = *(ushort2*)&T[row * 72 + c];
      *(ushort2*)(outp + row * 1024 + cp) = v2;
    }
  }
}

// ------------- flash attention: 64 q/wave, 4 waves/block (256 q), 256 thr,
// KBLK=32, K+V dbuf gll, register-resident P (permuted-V).  LDS = 32KB.
// Plain __launch_bounds__(256): allocator free (R7 proved 64q fits ~236 VGPR);
// 236<=256 -> 2 waves/SIMD -> 2 blocks x 4 waves = 8 waves/CU.
// QK^T in 2 qs-pairs bounds live regs; K reads 16 + V reads 8 per wave-kt
// serve 64 q (vs 32 reads per 64 q at R14's 32q/wave).
__global__ __launch_bounds__(256) void k_flash(const unsigned short* __restrict__ qb,
                                               const unsigned short* __restrict__ kb,
                                               const unsigned short* __restrict__ vtb,
                                               unsigned short* __restrict__ ob) {
  __shared__ __align__(16) unsigned short Ks[2][32][128];   // [key][d], 16B-slot swizzle ^(row&7)
  __shared__ __align__(16) unsigned short Vts[2][128][32];  // [d][key-slot], slot swz ^((row>>1)&3)
  const int bi = blockIdx.x;
  const int xcd = bi & 7, g = bi >> 3;                    // g in [0,64)
  const int bh = xcd + 8 * (g >> 2);
  const int q0 = (g & 3) * 256;
  const int tid = threadIdx.x, wave = tid >> 6, lane = tid & 63;
  const int lm = lane & 15, lg = lane >> 4, lk8 = lg * 8;
  const int sw = (lm & 7) << 4;                           // K read XOR (16 slots)
  const int pvsw = ((lm >> 1) & 3) << 4;                  // V read XOR (4 slots)
  const int b = bh >> 3, h = bh & 7;

  const unsigned short* kbh = kb + bh * 131072;
  const unsigned short* vbh = vtb + bh * 131072;

  // Q^T B-fragments for 4 q-subtiles (q pre-scaled by (1/32)*log2e in k_qkv)
  bf16x8 aq[4][4];
#pragma unroll
  for (int qs = 0; qs < 4; qs++) {
    const unsigned short* qrow = qb + (bh * 1024 + q0 + wave * 64 + qs * 16 + lm) * 128;
#pragma unroll
    for (int kc = 0; kc < 4; kc++) aq[qs][kc] = *(const bf16x8*)(qrow + kc * 32 + lk8);
  }

  f32x4 oacc[4][8];                                       // O^T[d=16dt+4lg+j][q=lm]
#pragma unroll
  for (int qs = 0; qs < 4; qs++)
#pragma unroll
    for (int dt = 0; dt < 8; dt++) oacc[qs][dt] = {0.f, 0.f, 0.f, 0.f};
  float mrun[4] = {0.f, 0.f, 0.f, 0.f};                   // log2 domain
  float lrun[4] = {0.f, 0.f, 0.f, 0.f};

  auto stage = [&](int kt, int buf) {
#pragma unroll
    for (int ii = 0; ii < 2; ii++) {            // K: 32 rows x 256B; wave covers 8 rows
      int krow = wave * 8 + ii * 4 + (lane >> 4);
      int c = (lane & 15) ^ (krow & 7);
      gll16(kbh + (kt * 32 + krow) * 128 + c * 8, &Ks[buf][wave * 8 + ii * 4][0]);
    }
#pragma unroll
    for (int ii = 0; ii < 2; ii++) {            // Vt: 128 rows x 64B; wave covers 32 rows
      int vrow = wave * 32 + ii * 16 + (lane >> 2);
      int c = (lane & 3) ^ ((vrow >> 1) & 3);
      gll16(vbh + vrow * 1024 + kt * 32 + c * 8, &Vts[buf][wave * 32 + ii * 16][0]);
    }
  };

  stage(0, 0);
  __syncthreads();
  int cur = 0;

  for (int kt = 0; kt < 32; kt++) {
    if (kt < 31) stage(kt + 1, cur ^ 1);        // async prefetch into other buffer
    __builtin_amdgcn_sched_barrier(0);          // keep gll issue ahead of compute

    unsigned int pw[4][2][2];                   // packed P, all indices compile-time

    // QK^T + softmax, processed in 2 qs-pairs to bound live registers
#pragma unroll
    for (int pr = 0; pr < 2; pr++) {
      // S^T = K · Q^T for qs = 2pr, 2pr+1 : lane holds S^T[16nt+4lg+j][q]
      f32x4 sc[2][2];
      __builtin_amdgcn_s_setprio(1);
#pragma unroll
      for (int nt = 0; nt < 2; nt++) {
        const char* krowp = (const char*)&Ks[cur][nt * 16 + lm][0];
        bf16x8 ak[4];
#pragma unroll
        for (int kc = 0; kc < 4; kc++)
          ak[kc] = *(const bf16x8*)(krowp + ((kc * 64 + lg * 16) ^ sw));
        f32x4 a0 = {0.f, 0.f, 0.f, 0.f}, a1 = {0.f, 0.f, 0.f, 0.f};
#pragma unroll
        for (int kc = 0; kc < 4; kc++) {
          a0 = __builtin_amdgcn_mfma_f32_16x16x32_bf16(ak[kc], aq[2 * pr][kc], a0, 0, 0, 0);
          a1 = __builtin_amdgcn_mfma_f32_16x16x32_bf16(ak[kc], aq[2 * pr + 1][kc], a1, 0, 0, 0);
        }
        sc[0][nt] = a0; sc[1][nt] = a1;
      }
      __builtin_amdgcn_s_setprio(0);

      // online softmax, base-2, defer-max (THR=8); P packed into registers
#pragma unroll
      for (int qq = 0; qq < 2; qq++) {
        const int qs = 2 * pr + qq;
        float mx8 = fmaxf(fmaxf(fmaxf(sc[qq][0][0], sc[qq][0][1]), fmaxf(sc[qq][0][2], sc[qq][0][3])),
                          fmaxf(fmaxf(sc[qq][1][0], sc[qq][1][1]), fmaxf(sc[qq][1][2], sc[qq][1][3])));
        if (!__all(mx8 <= mrun[qs] + 8.f)) {
          float mx = fmaxf(mx8, __shfl_xor(mx8, 16));
          mx = fmaxf(mx, __shfl_xor(mx, 32));
          float mnew = fmaxf(mrun[qs], mx);
          float corr = __builtin_exp2f(mrun[qs] - mnew);
          mrun[qs] = mnew;
          lrun[qs] *= corr;
#pragma unroll
          for (int dt = 0; dt < 8; dt++)
#pragma unroll
            for (int j = 0; j < 4; j++) oacc[qs][dt][j] *= corr;
        }
        float ts = 0.f;
#pragma unroll
        for (int nt = 0; nt < 2; nt++) {
          float e0 = __builtin_exp2f(sc[qq][nt][0] - mrun[qs]);
          float e1 = __builtin_exp2f(sc[qq][nt][1] - mrun[qs]);
          float e2 = __builtin_exp2f(sc[qq][nt][2] - mrun[qs]);
          float e3 = __builtin_exp2f(sc[qq][nt][3] - mrun[qs]);
          ts += (e0 + e1) + (e2 + e3);
          asm("v_cvt_pk_bf16_f32 %0, %1, %2" : "=v"(pw[qs][nt][0]) : "v"(e0), "v"(e1));
          asm("v_cvt_pk_bf16_f32 %0, %1, %2" : "=v"(pw[qs][nt][1]) : "v"(e2), "v"(e3));
        }
        lrun[qs] += ts;                          // lane-partial; reduced in epilogue
      }
    }

    // PV B-frags: lane (lm,lg) needs P[q][pi(8lg+i)] = its own pw dwords.
    bf16x8 pb[4];
#pragma unroll
    for (int qs = 0; qs < 4; qs++) {
      u32x4 t = {pw[qs][0][0], pw[qs][0][1], pw[qs][1][0], pw[qs][1][1]};
      pb[qs] = *(bf16x8*)&t;
    }

    // O^T += V^T · P^T  (V in pi-permuted key order; A/B k-orderings agree)
    __builtin_amdgcn_s_setprio(1);
#pragma unroll
    for (int dt = 0; dt < 8; dt++) {
      bf16x8 av = *(const bf16x8*)((const char*)&Vts[cur][dt * 16 + lm][0] + ((lg << 4) ^ pvsw));
#pragma unroll
      for (int qs = 0; qs < 4; qs++)
        oacc[qs][dt] = __builtin_amdgcn_mfma_f32_16x16x32_bf16(av, pb[qs], oacc[qs][dt], 0, 0, 0);
    }
    __builtin_amdgcn_s_setprio(0);

    __syncthreads();            // drains this kt's reads of cur AND gll writes to cur^1
    cur ^= 1;
  }

  // epilogue: reduce l across lane groups, O^T / l -> ob[B,N,H*128]
#pragma unroll
  for (int qs = 0; qs < 4; qs++) {
    float l = lrun[qs];
    l += __shfl_xor(l, 16);
    l += __shfl_xor(l, 32);
    float inv = 1.0f / l;
    unsigned short* orow = ob + ((b * 1024 + q0 + wave * 64 + qs * 16 + lm) * 8 + h) * 128;
#pragma unroll
    for (int dt = 0; dt < 8; dt++) {
#pragma unroll
      for (int pp = 0; pp < 2; pp++) {
        ushort2 o2;
        o2.x = f2bf(oacc[qs][dt][2 * pp]     * inv);
        o2.y = f2bf(oacc[qs][dt][2 * pp + 1] * inv);
        *(ushort2*)&orow[dt * 16 + 4 * lg + 2 * pp] = o2;
      }
    }
  }
}

// ------------- proj GEMM: [16384,1024] @ [1024,128] + bias -> fp32 ----------
// (byte-identical to R11/R13/R14)
__global__ __launch_bounds__(256) void k_proj(const unsigned short* __restrict__ ob,
                                              const unsigned short* __restrict__ wpt, // [128][1024]
                                              const float* __restrict__ bproj,
                                              float* __restrict__ out) {
  __shared__ __align__(16) unsigned short Os[2][64][128];
  __shared__ __align__(16) unsigned short Ws2[2][128][128];
  const int m0 = blockIdx.x * 64;
  const int tid = threadIdx.x, wave = tid >> 6, lane = tid & 63;
  const int lm = lane & 15, lg = lane >> 4;
  const int wr = wave >> 1, wc = wave & 1;

  auto stage = [&](int kt, int buf) {
#pragma unroll
    for (int ii = 0; ii < 4; ii++) {             // O tile: 64 rows x 256B
      int row = wave * 16 + ii * 4 + (lane >> 4);
      int c = (lane & 15) ^ (row & 7);
      gll16(ob + (m0 + row) * 1024 + kt * 128 + c * 8, &Os[buf][wave * 16 + ii * 4][0]);
    }
#pragma unroll
    for (int ii = 0; ii < 8; ii++) {             // W tile: 128 rows x 256B
      int row = wave * 32 + ii * 4 + (lane >> 4);
      int c = (lane & 15) ^ (row & 7);
      gll16(wpt + row * 1024 + kt * 128 + c * 8, &Ws2[buf][wave * 32 + ii * 4][0]);
    }
  };

  f32x4 acc[2][4];
#pragma unroll
  for (int i = 0; i < 2; i++)
#pragma unroll
    for (int j = 0; j < 4; j++) acc[i][j] = {0.f, 0.f, 0.f, 0.f};

  stage(0, 0);
  __syncthreads();
  int cur = 0;

  for (int kt = 0; kt < 8; kt++) {
    if (kt < 7) stage(kt + 1, cur ^ 1);
    __builtin_amdgcn_sched_barrier(0);
#pragma unroll
    for (int k32 = 0; k32 < 4; k32++) {
      bf16x8 af[2], bfr[4];
#pragma unroll
      for (int mi = 0; mi < 2; mi++) {
        int row = wr * 32 + mi * 16 + lm;
        af[mi] = *(const bf16x8*)((const char*)&Os[cur][row][0] + ((k32 * 64 + lg * 16) ^ ((lm & 7) << 4)));
      }
#pragma unroll
      for (int ni = 0; ni < 4; ni++) {
        int row = wc * 64 + ni * 16 + lm;
        bfr[ni] = *(const bf16x8*)((const char*)&Ws2[cur][row][0] + ((k32 * 64 + lg * 16) ^ ((lm & 7) << 4)));
      }
#pragma unroll
      for (int mi = 0; mi < 2; mi++)
#pragma unroll
        for (int ni = 0; ni < 4; ni++)
          acc[mi][ni] = __builtin_amdgcn_mfma_f32_16x16x32_bf16(af[mi], bfr[ni], acc[mi][ni], 0, 0, 0);
    }
    __syncthreads();
    cur ^= 1;
  }

#pragma unroll
  for (int mi = 0; mi < 2; mi++)
#pragma unroll
    for (int ni = 0; ni < 4; ni++)
#pragma unroll
      for (int j = 0; j < 4; j++) {
        int m = m0 + wr * 32 + mi * 16 + 4 * (lane >> 4) + j;
        int n = wc * 64 + ni * 16 + lm;
        out[m * 128 + n] = acc[mi][ni][j] + bproj[n];
      }
}

extern "C" void kernel_launch(void* const* d_in, const int* in_sizes, int n_in,
                              void* d_out, int out_size, void* d_ws, size_t ws_size,
                              hipStream_t stream) {
  const float* x     = (const float*)d_in[0];
  const float* gamma = (const float*)d_in[1];
  const float* beta  = (const float*)d_in[2];
  const float* wqkv  = (const float*)d_in[3];
  const float* wproj = (const float*)d_in[4];
  const float* bproj = (const float*)d_in[5];
  float* out = (float*)d_out;

  unsigned short* ws = (unsigned short*)d_ws;
  unsigned short* xb     = ws;                       // 16384*128      = 2,097,152
  unsigned short* wqkvT  = xb + 2097152;             // 3072*128       =   393,216
  unsigned short* wprojT = wqkvT + 393216;           // 128*1024       =   131,072
  unsigned short* qbuf   = wprojT + 131072;          // 16*8*1024*128  = 16,777,216
  unsigned short* kbuf   = qbuf + 16777216;
  unsigned short* vtbuf  = kbuf + 16777216;
  unsigned short* obuf   = vtbuf + 16777216;         // total ~139.5 MB

  hipLaunchKernelGGL(k_prep, dim3(4152),    dim3(256), 0, stream, x, gamma, beta, wqkv, wproj, xb, wqkvT, wprojT);
  hipLaunchKernelGGL(k_qkv,  dim3(256, 24), dim3(256), 0, stream, xb, wqkvT, qbuf, kbuf, vtbuf);
  hipLaunchKernelGGL(k_flash, dim3(512),    dim3(256), 0, stream, qbuf, kbuf, vtbuf, obuf);
  hipLaunchKernelGGL(k_proj, dim3(256),     dim3(256), 0, stream, obuf, wprojT, bproj, out);
}

// Round 18
// 160.567 us; speedup vs baseline: 1.2575x; 1.2575x over previous
//
#include <hip/hip_runtime.h>
#include <hip/hip_bf16.h>

// Problem: B=16, N=1024, EMB=128, H=8, INNER=1024
// out = proj( attention( LN(x) @ Wqkv ) ) + b_proj,  fp32 in/out, bf16-tolerance.
// R18 = R14 (measured best: 161.4us). 32q/wave flash, register-resident P via
// key-permuted V, KBLK=32 K+V dbuf gll, 80 VGPR / 32KB LDS.

typedef __attribute__((ext_vector_type(8))) short bf16x8;
typedef __attribute__((ext_vector_type(4))) float f32x4;
typedef __attribute__((ext_vector_type(4))) unsigned int u32x4;

__device__ __forceinline__ unsigned short f2bf(float f) {
  unsigned int u = __float_as_uint(f);
  u += 0x7FFF + ((u >> 16) & 1);   // round-nearest-even
  return (unsigned short)(u >> 16);
}

// async global->LDS, 16B per lane; LDS dest = wave-uniform base + lane*16
__device__ __forceinline__ void gll16(const void* g, void* l) {
  __builtin_amdgcn_global_load_lds((const __attribute__((address_space(1))) unsigned int*)g,
                                   (__attribute__((address_space(3))) unsigned int*)l, 16, 0, 0);
}

// ---------------- merged prep: LN (blocks 0..4095), wqkv cast-T (4096..4143),
// ---------------- wproj cast-T (4144..4151)
__global__ __launch_bounds__(256) void k_prep(const float* __restrict__ x,
                                              const float* __restrict__ gamma,
                                              const float* __restrict__ beta,
                                              const float* __restrict__ wqkv,
                                              const float* __restrict__ wproj,
                                              unsigned short* __restrict__ xb,
                                              unsigned short* __restrict__ wqkvT,
                                              unsigned short* __restrict__ wprojT) {
  __shared__ unsigned short T[17152];            // 128*134 shorts, reused per branch
  const int bid = blockIdx.x, tid = threadIdx.x;
  if (bid < 4096) {
    int row  = bid * 4 + (tid >> 6);
    int lane = tid & 63;
    float2 v = *reinterpret_cast<const float2*>(x + row * 128 + lane * 2);
    float s = v.x + v.y, ss = v.x * v.x + v.y * v.y;
#pragma unroll
    for (int m = 1; m < 64; m <<= 1) { s += __shfl_xor(s, m); ss += __shfl_xor(ss, m); }
    float mu   = s * (1.0f / 128.0f);
    float var  = ss * (1.0f / 128.0f) - mu * mu;
    float rstd = rsqrtf(var + 1e-5f);
    float2 g  = *reinterpret_cast<const float2*>(gamma + lane * 2);
    float2 be = *reinterpret_cast<const float2*>(beta + lane * 2);
    ushort2 o;
    o.x = f2bf((v.x - mu) * rstd * g.x + be.x);
    o.y = f2bf((v.y - mu) * rstd * g.y + be.y);
    *reinterpret_cast<ushort2*>(xb + row * 128 + lane * 2) = o;
  } else if (bid < 4144) {
    const int n0 = (bid - 4096) * 64;            // w_qkv [128][3072] -> [3072][128]
#pragma unroll
    for (int i = 0; i < 32; i++) {
      int idx = i * 256 + tid;
      int k = idx >> 6, c = idx & 63;
      T[k * 70 + c] = f2bf(wqkv[k * 3072 + n0 + c]);
    }
    __syncthreads();
#pragma unroll
    for (int i = 0; i < 32; i++) {
      int idx = i * 256 + tid;
      int n = idx >> 7, k = idx & 127;
      wqkvT[(n0 + n) * 128 + k] = T[k * 70 + n];
    }
  } else {
    const int k0 = (bid - 4144) * 128;           // w_proj [1024][128] -> [128][1024]
#pragma unroll
    for (int i = 0; i < 64; i++) {
      int idx = i * 256 + tid;
      int r = idx >> 7, c = idx & 127;
      T[r * 134 + c] = f2bf(wproj[(k0 + r) * 128 + c]);
    }
    __syncthreads();
#pragma unroll
    for (int i = 0; i < 64; i++) {
      int idx = i * 256 + tid;
      int c = idx >> 7, r = idx & 127;
      wprojT[c * 1024 + k0 + r] = T[r * 134 + c];
    }
  }
}

// ------------- QKV GEMM: [16384,128] @ [128,3072]; writes Q,K [B,H,N,D], Vt [B,H,D,N]
// M-tile 64, 48KB LDS (3 blocks/CU). V is stored with seq PERMUTED within each
// 32-key tile: position p holds key pi(p), pi(8g+i) = i<4 ? 4g+i : 16+4g+(i-4).
__global__ __launch_bounds__(256) void k_qkv(const unsigned short* __restrict__ xb,
                                             const unsigned short* __restrict__ wt,  // [3072][128]
                                             unsigned short* __restrict__ qb,
                                             unsigned short* __restrict__ kb,
                                             unsigned short* __restrict__ vtb) {
  __shared__ __align__(16) unsigned short SH[24576];   // 48KB
  unsigned short* Xs = SH;                        // [64][128]
  unsigned short* Ws = SH + 8192;                 // [128][128]
  const int m0 = blockIdx.x * 64;
  const int n0 = blockIdx.y * 128;
  const int tid = threadIdx.x, wave = tid >> 6, lane = tid & 63;
  const int lm = lane & 15, lg = lane >> 4;
  const int wr = wave >> 1, wc = wave & 1;

#pragma unroll
  for (int ii = 0; ii < 4; ii++) {                // X: 16 rows per wave
    int row = wave * 16 + ii * 4 + (lane >> 4);
    int c = (lane & 15) ^ (row & 7);
    gll16(xb + (m0 + row) * 128 + c * 8, Xs + (wave * 16 + ii * 4) * 128);
  }
#pragma unroll
  for (int ii = 0; ii < 8; ii++) {                // W: 32 rows per wave
    int row = wave * 32 + ii * 4 + (lane >> 4);
    int c = (lane & 15) ^ (row & 7);
    gll16(wt + (n0 + row) * 128 + c * 8, Ws + (wave * 32 + ii * 4) * 128);
  }
  __syncthreads();

  f32x4 acc[2][4];
#pragma unroll
  for (int i = 0; i < 2; i++)
#pragma unroll
    for (int j = 0; j < 4; j++) acc[i][j] = {0.f, 0.f, 0.f, 0.f};

#pragma unroll
  for (int k32 = 0; k32 < 4; k32++) {
    bf16x8 af[2], bfr[4];
#pragma unroll
    for (int mi = 0; mi < 2; mi++) {
      int row = wr * 32 + mi * 16 + lm;
      af[mi] = *(const bf16x8*)((const char*)(Xs + row * 128) + ((k32 * 64 + lg * 16) ^ ((lm & 7) << 4)));
    }
#pragma unroll
    for (int ni = 0; ni < 4; ni++) {
      int row = wc * 64 + ni * 16 + lm;
      bfr[ni] = *(const bf16x8*)((const char*)(Ws + row * 128) + ((k32 * 64 + lg * 16) ^ ((lm & 7) << 4)));
    }
#pragma unroll
    for (int mi = 0; mi < 2; mi++)
#pragma unroll
      for (int ni = 0; ni < 4; ni++)
        acc[mi][ni] = __builtin_amdgcn_mfma_f32_16x16x32_bf16(af[mi], bfr[ni], acc[mi][ni], 0, 0, 0);
  }

  // epilogue: repack through LDS for coalesced stores.
  __syncthreads();
  unsigned short* T = SH;
  const int isV = (n0 >= 2048);
  const float qscale = (n0 < 1024) ? 0.04508422f : 1.0f;
#pragma unroll
  for (int mi = 0; mi < 2; mi++)
#pragma unroll
    for (int ni = 0; ni < 4; ni++)
#pragma unroll
      for (int j = 0; j < 4; j++) {
        int mloc = wr * 32 + mi * 16 + 4 * lg + j;
        int nloc = wc * 64 + ni * 16 + lm;
        unsigned short v = f2bf(acc[mi][ni][j] * qscale);
        if (isV) T[nloc * 72 + mloc] = v;
        else     T[mloc * 136 + nloc] = v;
      }
  __syncthreads();
  const int bb = m0 >> 10, seq0 = m0 & 1023;
  const int hh = (n0 & 1023) >> 7;
  const int bh = bb * 8 + hh;
  if (!isV) {
    unsigned short* outp = (n0 < 1024) ? (qb + (bh * 1024 + seq0) * 128)
                                       : (kb + (bh * 1024 + seq0) * 128);
#pragma unroll
    for (int i = 0; i < 16; i++) {                // 64 rows x 128 cols
      int flat = i * 512 + tid * 2;
      int row = flat >> 7, c = flat & 127;
      ushort2 v2 = *(ushort2*)&T[row * 136 + c];
      *(ushort2*)(outp + row * 128 + c) = v2;
    }
  } else {
    unsigned short* outp = vtb + bh * 131072 + seq0;
#pragma unroll
    for (int i = 0; i < 16; i++) {                // 128 rows(d) x 64 cols(seq), permuted
      int flat = i * 512 + tid * 2;
      int row = flat >> 6, c = flat & 63;
      int k = c & 31;
      int p = ((k & 12) << 1) | ((k >> 4) << 2) | (k & 3);   // pi^-1(key)
      int cp = (c & 32) | p;
      ushort2 v2 = *(ushort2*)&T[row * 72 + c];
      *(ushort2*)(outp + row * 1024 + cp) = v2;
    }
  }
}

// ------------- flash attention: 32 q/wave, 128 q/block, KBLK=32, K+V dbuf gll,
// register-resident P (key-permuted V layout makes PV B-frag lane-local).
// LDS = 16 (K dbuf) + 16 (V dbuf) = 32KB.  VGPR ~80 -> 8 waves/CU.
__global__ __launch_bounds__(256, 3) void k_flash(const unsigned short* __restrict__ qb,
                                                  const unsigned short* __restrict__ kb,
                                                  const unsigned short* __restrict__ vtb,
                                                  unsigned short* __restrict__ ob) {
  __shared__ __align__(16) unsigned short Ks[2][32][128];   // [key][d], 16B-slot swizzle ^(row&7)
  __shared__ __align__(16) unsigned short Vts[2][128][32];  // [d][key-slot], slot swz ^((row>>1)&3)
  const int bi = blockIdx.x;
  const int xcd = bi & 7, g = bi >> 3;                    // g in [0,128)
  const int bh = xcd + 8 * (g >> 3);
  const int q0 = (g & 7) * 128;
  const int tid = threadIdx.x, wave = tid >> 6, lane = tid & 63;
  const int lm = lane & 15, lg = lane >> 4, lk8 = lg * 8;
  const int sw = (lm & 7) << 4;                           // K read XOR (16 slots)
  const int pvsw = ((lm >> 1) & 3) << 4;                  // V read XOR (4 slots)
  const int b = bh >> 3, h = bh & 7;

  const unsigned short* kbh = kb + bh * 131072;
  const unsigned short* vbh = vtb + bh * 131072;

  // Q^T B-fragments for 2 q-subtiles (q pre-scaled by (1/32)*log2e in k_qkv)
  bf16x8 aq[2][4];
#pragma unroll
  for (int qs = 0; qs < 2; qs++) {
    const unsigned short* qrow = qb + (bh * 1024 + q0 + wave * 32 + qs * 16 + lm) * 128;
#pragma unroll
    for (int kc = 0; kc < 4; kc++) aq[qs][kc] = *(const bf16x8*)(qrow + kc * 32 + lk8);
  }

  f32x4 oacc[2][8];                                       // O^T[d=16dt+4lg+j][q=lm]
#pragma unroll
  for (int qs = 0; qs < 2; qs++)
#pragma unroll
    for (int dt = 0; dt < 8; dt++) oacc[qs][dt] = {0.f, 0.f, 0.f, 0.f};
  float mrun[2] = {0.f, 0.f}, lrun[2] = {0.f, 0.f};       // log2 domain

  auto stage = [&](int kt, int buf) {
#pragma unroll
    for (int ii = 0; ii < 2; ii++) {            // K: 32 rows x 256B; wave covers 8 rows
      int krow = wave * 8 + ii * 4 + (lane >> 4);
      int c = (lane & 15) ^ (krow & 7);
      gll16(kbh + (kt * 32 + krow) * 128 + c * 8, &Ks[buf][wave * 8 + ii * 4][0]);
    }
#pragma unroll
    for (int ii = 0; ii < 2; ii++) {            // Vt: 128 rows x 64B; wave covers 32 rows
      int vrow = wave * 32 + ii * 16 + (lane >> 2);
      int c = (lane & 3) ^ ((vrow >> 1) & 3);
      gll16(vbh + vrow * 1024 + kt * 32 + c * 8, &Vts[buf][wave * 32 + ii * 16][0]);
    }
  };

  stage(0, 0);
  __syncthreads();
  int cur = 0;

  for (int kt = 0; kt < 32; kt++) {
    if (kt < 31) stage(kt + 1, cur ^ 1);        // async prefetch into other buffer
    __builtin_amdgcn_sched_barrier(0);          // keep gll issue ahead of compute

    // S^T = K · Q^T : lane holds S^T[16nt+4lg+j][q=qs*16+lm] (log2 domain)
    f32x4 sc[2][2];
    __builtin_amdgcn_s_setprio(1);
#pragma unroll
    for (int nt = 0; nt < 2; nt++) {
      f32x4 a0 = {0.f, 0.f, 0.f, 0.f}, a1 = {0.f, 0.f, 0.f, 0.f};
      const char* krowp = (const char*)&Ks[cur][nt * 16 + lm][0];
#pragma unroll
      for (int kc = 0; kc < 4; kc++) {
        bf16x8 ak = *(const bf16x8*)(krowp + ((kc * 64 + lg * 16) ^ sw));
        a0 = __builtin_amdgcn_mfma_f32_16x16x32_bf16(ak, aq[0][kc], a0, 0, 0, 0);
        a1 = __builtin_amdgcn_mfma_f32_16x16x32_bf16(ak, aq[1][kc], a1, 0, 0, 0);
      }
      sc[0][nt] = a0; sc[1][nt] = a1;
    }
    __builtin_amdgcn_s_setprio(0);

    // online softmax per q-subtile, base-2, defer-max (THR=8); P stays in registers.
    unsigned int pw[2][2][2];                   // [qs][nt][w], all indices compile-time
#pragma unroll
    for (int qs = 0; qs < 2; qs++) {
      float mx8 = fmaxf(fmaxf(fmaxf(sc[qs][0][0], sc[qs][0][1]), fmaxf(sc[qs][0][2], sc[qs][0][3])),
                        fmaxf(fmaxf(sc[qs][1][0], sc[qs][1][1]), fmaxf(sc[qs][1][2], sc[qs][1][3])));
      if (!__all(mx8 <= mrun[qs] + 8.f)) {
        float mx = fmaxf(mx8, __shfl_xor(mx8, 16));
        mx = fmaxf(mx, __shfl_xor(mx, 32));
        float mnew = fmaxf(mrun[qs], mx);
        float corr = __builtin_exp2f(mrun[qs] - mnew);
        mrun[qs] = mnew;
        lrun[qs] *= corr;
#pragma unroll
        for (int dt = 0; dt < 8; dt++)
#pragma unroll
          for (int j = 0; j < 4; j++) oacc[qs][dt][j] *= corr;
      }
      float ts = 0.f;
#pragma unroll
      for (int nt = 0; nt < 2; nt++) {
        float e0 = __builtin_exp2f(sc[qs][nt][0] - mrun[qs]);
        float e1 = __builtin_exp2f(sc[qs][nt][1] - mrun[qs]);
        float e2 = __builtin_exp2f(sc[qs][nt][2] - mrun[qs]);
        float e3 = __builtin_exp2f(sc[qs][nt][3] - mrun[qs]);
        ts += (e0 + e1) + (e2 + e3);
        asm("v_cvt_pk_bf16_f32 %0, %1, %2" : "=v"(pw[qs][nt][0]) : "v"(e0), "v"(e1));
        asm("v_cvt_pk_bf16_f32 %0, %1, %2" : "=v"(pw[qs][nt][1]) : "v"(e2), "v"(e3));
      }
      lrun[qs] += ts;                            // lane-partial; reduced in epilogue
    }

    // PV B-frags: lane (lm,lg) needs P[q=qs*16+lm][pi(8lg+i)] = its own pw dwords.
    u32x4 t0 = {pw[0][0][0], pw[0][0][1], pw[0][1][0], pw[0][1][1]};
    u32x4 t1 = {pw[1][0][0], pw[1][0][1], pw[1][1][0], pw[1][1][1]};
    bf16x8 pb0 = *(bf16x8*)&t0;
    bf16x8 pb1 = *(bf16x8*)&t1;

    // O^T += V^T · P^T  (V in pi-permuted key order; A/B k-orderings agree)
    __builtin_amdgcn_s_setprio(1);
#pragma unroll
    for (int dt = 0; dt < 8; dt++) {
      bf16x8 av = *(const bf16x8*)((const char*)&Vts[cur][dt * 16 + lm][0] + ((lg << 4) ^ pvsw));
      oacc[0][dt] = __builtin_amdgcn_mfma_f32_16x16x32_bf16(av, pb0, oacc[0][dt], 0, 0, 0);
      oacc[1][dt] = __builtin_amdgcn_mfma_f32_16x16x32_bf16(av, pb1, oacc[1][dt], 0, 0, 0);
    }
    __builtin_amdgcn_s_setprio(0);

    __syncthreads();            // drains this kt's reads of cur AND gll writes to cur^1
    cur ^= 1;
  }

  // epilogue: reduce l across lane groups, O^T / l -> ob[B,N,H*128]
#pragma unroll
  for (int qs = 0; qs < 2; qs++) {
    float l = lrun[qs];
    l += __shfl_xor(l, 16);
    l += __shfl_xor(l, 32);
    float inv = 1.0f / l;
    unsigned short* orow = ob + ((b * 1024 + q0 + wave * 32 + qs * 16 + lm) * 8 + h) * 128;
#pragma unroll
    for (int dt = 0; dt < 8; dt++) {
#pragma unroll
      for (int pp = 0; pp < 2; pp++) {
        ushort2 o2;
        o2.x = f2bf(oacc[qs][dt][2 * pp]     * inv);
        o2.y = f2bf(oacc[qs][dt][2 * pp + 1] * inv);
        *(ushort2*)&orow[dt * 16 + 4 * lg + 2 * pp] = o2;
      }
    }
  }
}

// ------------- proj GEMM: [16384,1024] @ [1024,128] + bias -> fp32 ----------
__global__ __launch_bounds__(256) void k_proj(const unsigned short* __restrict__ ob,
                                              const unsigned short* __restrict__ wpt, // [128][1024]
                                              const float* __restrict__ bproj,
                                              float* __restrict__ out) {
  __shared__ __align__(16) unsigned short Os[2][64][128];
  __shared__ __align__(16) unsigned short Ws2[2][128][128];
  const int m0 = blockIdx.x * 64;
  const int tid = threadIdx.x, wave = tid >> 6, lane = tid & 63;
  const int lm = lane & 15, lg = lane >> 4;
  const int wr = wave >> 1, wc = wave & 1;

  auto stage = [&](int kt, int buf) {
#pragma unroll
    for (int ii = 0; ii < 4; ii++) {             // O tile: 64 rows x 256B
      int row = wave * 16 + ii * 4 + (lane >> 4);
      int c = (lane & 15) ^ (row & 7);
      gll16(ob + (m0 + row) * 1024 + kt * 128 + c * 8, &Os[buf][wave * 16 + ii * 4][0]);
    }
#pragma unroll
    for (int ii = 0; ii < 8; ii++) {             // W tile: 128 rows x 256B
      int row = wave * 32 + ii * 4 + (lane >> 4);
      int c = (lane & 15) ^ (row & 7);
      gll16(wpt + row * 1024 + kt * 128 + c * 8, &Ws2[buf][wave * 32 + ii * 4][0]);
    }
  };

  f32x4 acc[2][4];
#pragma unroll
  for (int i = 0; i < 2; i++)
#pragma unroll
    for (int j = 0; j < 4; j++) acc[i][j] = {0.f, 0.f, 0.f, 0.f};

  stage(0, 0);
  __syncthreads();
  int cur = 0;

  for (int kt = 0; kt < 8; kt++) {
    if (kt < 7) stage(kt + 1, cur ^ 1);
    __builtin_amdgcn_sched_barrier(0);
#pragma unroll
    for (int k32 = 0; k32 < 4; k32++) {
      bf16x8 af[2], bfr[4];
#pragma unroll
      for (int mi = 0; mi < 2; mi++) {
        int row = wr * 32 + mi * 16 + lm;
        af[mi] = *(const bf16x8*)((const char*)&Os[cur][row][0] + ((k32 * 64 + lg * 16) ^ ((lm & 7) << 4)));
      }
#pragma unroll
      for (int ni = 0; ni < 4; ni++) {
        int row = wc * 64 + ni * 16 + lm;
        bfr[ni] = *(const bf16x8*)((const char*)&Ws2[cur][row][0] + ((k32 * 64 + lg * 16) ^ ((lm & 7) << 4)));
      }
#pragma unroll
      for (int mi = 0; mi < 2; mi++)
#pragma unroll
        for (int ni = 0; ni < 4; ni++)
          acc[mi][ni] = __builtin_amdgcn_mfma_f32_16x16x32_bf16(af[mi], bfr[ni], acc[mi][ni], 0, 0, 0);
    }
    __syncthreads();
    cur ^= 1;
  }

#pragma unroll
  for (int mi = 0; mi < 2; mi++)
#pragma unroll
    for (int ni = 0; ni < 4; ni++)
#pragma unroll
      for (int j = 0; j < 4; j++) {
        int m = m0 + wr * 32 + mi * 16 + 4 * (lane >> 4) + j;
        int n = wc * 64 + ni * 16 + lm;
        out[m * 128 + n] = acc[mi][ni][j] + bproj[n];
      }
}

extern "C" void kernel_launch(void* const* d_in, const int* in_sizes, int n_in,
                              void* d_out, int out_size, void* d_ws, size_t ws_size,
                              hipStream_t stream) {
  const float* x     = (const float*)d_in[0];
  const float* gamma = (const float*)d_in[1];
  const float* beta  = (const float*)d_in[2];
  const float* wqkv  = (const float*)d_in[3];
  const float* wproj = (const float*)d_in[4];
  const float* bproj = (const float*)d_in[5];
  float* out = (float*)d_out;

  unsigned short* ws = (unsigned short*)d_ws;
  unsigned short* xb     = ws;                       // 16384*128      = 2,097,152
  unsigned short* wqkvT  = xb + 2097152;             // 3072*128       =   393,216
  unsigned short* wprojT = wqkvT + 393216;           // 128*1024       =   131,072
  unsigned short* qbuf   = wprojT + 131072;          // 16*8*1024*128  = 16,777,216
  unsigned short* kbuf   = qbuf + 16777216;
  unsigned short* vtbuf  = kbuf + 16777216;
  unsigned short* obuf   = vtbuf + 16777216;         // total ~139.5 MB

  hipLaunchKernelGGL(k_prep, dim3(4152),    dim3(256), 0, stream, x, gamma, beta, wqkv, wproj, xb, wqkvT, wprojT);
  hipLaunchKernelGGL(k_qkv,  dim3(256, 24), dim3(256), 0, stream, xb, wqkvT, qbuf, kbuf, vtbuf);
  hipLaunchKernelGGL(k_flash, dim3(1024),   dim3(256), 0, stream, qbuf, kbuf, vtbuf, obuf);
  hipLaunchKernelGGL(k_proj, dim3(256),     dim3(256), 0, stream, obuf, wprojT, bproj, out);
}

// Round 19
// 159.694 us; speedup vs baseline: 1.2644x; 1.0055x over previous
//
#include <hip/hip_runtime.h>
#include <hip/hip_bf16.h>

// Problem: B=16, N=1024, EMB=128, H=8, INNER=1024
// out = proj( attention( LN(x) @ Wqkv ) ) + b_proj,  fp32 in/out, bf16-tolerance.
// R19 = R18 flash with KBLK=64 (2x32-key halves), ONE barrier per 64 keys.

typedef __attribute__((ext_vector_type(8))) short bf16x8;
typedef __attribute__((ext_vector_type(4))) float f32x4;
typedef __attribute__((ext_vector_type(4))) unsigned int u32x4;

__device__ __forceinline__ unsigned short f2bf(float f) {
  unsigned int u = __float_as_uint(f);
  u += 0x7FFF + ((u >> 16) & 1);   // round-nearest-even
  return (unsigned short)(u >> 16);
}

// async global->LDS, 16B per lane; LDS dest = wave-uniform base + lane*16
__device__ __forceinline__ void gll16(const void* g, void* l) {
  __builtin_amdgcn_global_load_lds((const __attribute__((address_space(1))) unsigned int*)g,
                                   (__attribute__((address_space(3))) unsigned int*)l, 16, 0, 0);
}

// ---------------- merged prep: LN (blocks 0..4095), wqkv cast-T (4096..4143),
// ---------------- wproj cast-T (4144..4151)
__global__ __launch_bounds__(256) void k_prep(const float* __restrict__ x,
                                              const float* __restrict__ gamma,
                                              const float* __restrict__ beta,
                                              const float* __restrict__ wqkv,
                                              const float* __restrict__ wproj,
                                              unsigned short* __restrict__ xb,
                                              unsigned short* __restrict__ wqkvT,
                                              unsigned short* __restrict__ wprojT) {
  __shared__ unsigned short T[17152];            // 128*134 shorts, reused per branch
  const int bid = blockIdx.x, tid = threadIdx.x;
  if (bid < 4096) {
    int row  = bid * 4 + (tid >> 6);
    int lane = tid & 63;
    float2 v = *reinterpret_cast<const float2*>(x + row * 128 + lane * 2);
    float s = v.x + v.y, ss = v.x * v.x + v.y * v.y;
#pragma unroll
    for (int m = 1; m < 64; m <<= 1) { s += __shfl_xor(s, m); ss += __shfl_xor(ss, m); }
    float mu   = s * (1.0f / 128.0f);
    float var  = ss * (1.0f / 128.0f) - mu * mu;
    float rstd = rsqrtf(var + 1e-5f);
    float2 g  = *reinterpret_cast<const float2*>(gamma + lane * 2);
    float2 be = *reinterpret_cast<const float2*>(beta + lane * 2);
    ushort2 o;
    o.x = f2bf((v.x - mu) * rstd * g.x + be.x);
    o.y = f2bf((v.y - mu) * rstd * g.y + be.y);
    *reinterpret_cast<ushort2*>(xb + row * 128 + lane * 2) = o;
  } else if (bid < 4144) {
    const int n0 = (bid - 4096) * 64;            // w_qkv [128][3072] -> [3072][128]
#pragma unroll
    for (int i = 0; i < 32; i++) {
      int idx = i * 256 + tid;
      int k = idx >> 6, c = idx & 63;
      T[k * 70 + c] = f2bf(wqkv[k * 3072 + n0 + c]);
    }
    __syncthreads();
#pragma unroll
    for (int i = 0; i < 32; i++) {
      int idx = i * 256 + tid;
      int n = idx >> 7, k = idx & 127;
      wqkvT[(n0 + n) * 128 + k] = T[k * 70 + n];
    }
  } else {
    const int k0 = (bid - 4144) * 128;           // w_proj [1024][128] -> [128][1024]
#pragma unroll
    for (int i = 0; i < 64; i++) {
      int idx = i * 256 + tid;
      int r = idx >> 7, c = idx & 127;
      T[r * 134 + c] = f2bf(wproj[(k0 + r) * 128 + c]);
    }
    __syncthreads();
#pragma unroll
    for (int i = 0; i < 64; i++) {
      int idx = i * 256 + tid;
      int c = idx >> 7, r = idx & 127;
      wprojT[c * 1024 + k0 + r] = T[r * 134 + c];
    }
  }
}

// ------------- QKV GEMM: [16384,128] @ [128,3072]; writes Q,K [B,H,N,D], Vt [B,H,D,N]
// (byte-identical to R14/R18: M-tile 64, 48KB LDS, V seq-permuted per 32-key tile)
__global__ __launch_bounds__(256) void k_qkv(const unsigned short* __restrict__ xb,
                                             const unsigned short* __restrict__ wt,  // [3072][128]
                                             unsigned short* __restrict__ qb,
                                             unsigned short* __restrict__ kb,
                                             unsigned short* __restrict__ vtb) {
  __shared__ __align__(16) unsigned short SH[24576];   // 48KB
  unsigned short* Xs = SH;                        // [64][128]
  unsigned short* Ws = SH + 8192;                 // [128][128]
  const int m0 = blockIdx.x * 64;
  const int n0 = blockIdx.y * 128;
  const int tid = threadIdx.x, wave = tid >> 6, lane = tid & 63;
  const int lm = lane & 15, lg = lane >> 4;
  const int wr = wave >> 1, wc = wave & 1;

#pragma unroll
  for (int ii = 0; ii < 4; ii++) {                // X: 16 rows per wave
    int row = wave * 16 + ii * 4 + (lane >> 4);
    int c = (lane & 15) ^ (row & 7);
    gll16(xb + (m0 + row) * 128 + c * 8, Xs + (wave * 16 + ii * 4) * 128);
  }
#pragma unroll
  for (int ii = 0; ii < 8; ii++) {                // W: 32 rows per wave
    int row = wave * 32 + ii * 4 + (lane >> 4);
    int c = (lane & 15) ^ (row & 7);
    gll16(wt + (n0 + row) * 128 + c * 8, Ws + (wave * 32 + ii * 4) * 128);
  }
  __syncthreads();

  f32x4 acc[2][4];
#pragma unroll
  for (int i = 0; i < 2; i++)
#pragma unroll
    for (int j = 0; j < 4; j++) acc[i][j] = {0.f, 0.f, 0.f, 0.f};

#pragma unroll
  for (int k32 = 0; k32 < 4; k32++) {
    bf16x8 af[2], bfr[4];
#pragma unroll
    for (int mi = 0; mi < 2; mi++) {
      int row = wr * 32 + mi * 16 + lm;
      af[mi] = *(const bf16x8*)((const char*)(Xs + row * 128) + ((k32 * 64 + lg * 16) ^ ((lm & 7) << 4)));
    }
#pragma unroll
    for (int ni = 0; ni < 4; ni++) {
      int row = wc * 64 + ni * 16 + lm;
      bfr[ni] = *(const bf16x8*)((const char*)(Ws + row * 128) + ((k32 * 64 + lg * 16) ^ ((lm & 7) << 4)));
    }
#pragma unroll
    for (int mi = 0; mi < 2; mi++)
#pragma unroll
      for (int ni = 0; ni < 4; ni++)
        acc[mi][ni] = __builtin_amdgcn_mfma_f32_16x16x32_bf16(af[mi], bfr[ni], acc[mi][ni], 0, 0, 0);
  }

  // epilogue: repack through LDS for coalesced stores.
  __syncthreads();
  unsigned short* T = SH;
  const int isV = (n0 >= 2048);
  const float qscale = (n0 < 1024) ? 0.04508422f : 1.0f;
#pragma unroll
  for (int mi = 0; mi < 2; mi++)
#pragma unroll
    for (int ni = 0; ni < 4; ni++)
#pragma unroll
      for (int j = 0; j < 4; j++) {
        int mloc = wr * 32 + mi * 16 + 4 * lg + j;
        int nloc = wc * 64 + ni * 16 + lm;
        unsigned short v = f2bf(acc[mi][ni][j] * qscale);
        if (isV) T[nloc * 72 + mloc] = v;
        else     T[mloc * 136 + nloc] = v;
      }
  __syncthreads();
  const int bb = m0 >> 10, seq0 = m0 & 1023;
  const int hh = (n0 & 1023) >> 7;
  const int bh = bb * 8 + hh;
  if (!isV) {
    unsigned short* outp = (n0 < 1024) ? (qb + (bh * 1024 + seq0) * 128)
                                       : (kb + (bh * 1024 + seq0) * 128);
#pragma unroll
    for (int i = 0; i < 16; i++) {                // 64 rows x 128 cols
      int flat = i * 512 + tid * 2;
      int row = flat >> 7, c = flat & 127;
      ushort2 v2 = *(ushort2*)&T[row * 136 + c];
      *(ushort2*)(outp + row * 128 + c) = v2;
    }
  } else {
    unsigned short* outp = vtb + bh * 131072 + seq0;
#pragma unroll
    for (int i = 0; i < 16; i++) {                // 128 rows(d) x 64 cols(seq), permuted
      int flat = i * 512 + tid * 2;
      int row = flat >> 6, c = flat & 63;
      int k = c & 31;
      int p = ((k & 12) << 1) | ((k >> 4) << 2) | (k & 3);   // pi^-1(key)
      int cp = (c & 32) | p;
      ushort2 v2 = *(ushort2*)&T[row * 72 + c];
      *(ushort2*)(outp + row * 1024 + cp) = v2;
    }
  }
}

// ------------- flash attention: 32 q/wave, 128 q/block, KBLK=64 (2x32 halves),
// K+V dbuf gll, register-resident P (key-permuted V), ONE barrier per 64 keys.
// LDS = 32 (K dbuf) + 32 (V dbuf) = 64KB -> 2 blocks/CU (128KB <= ~144KB usable).
__global__ __launch_bounds__(256, 3) void k_flash(const unsigned short* __restrict__ qb,
                                                  const unsigned short* __restrict__ kb,
                                                  const unsigned short* __restrict__ vtb,
                                                  unsigned short* __restrict__ ob) {
  __shared__ __align__(16) unsigned short Ks[2][64][128];   // [key][d], 16B-slot swizzle ^(row&7)
  __shared__ __align__(16) unsigned short Vts[2][128][64];  // [d][key-slot], slot swz ^(row&7)
  const int bi = blockIdx.x;
  const int xcd = bi & 7, g = bi >> 3;                    // g in [0,128)
  const int bh = xcd + 8 * (g >> 3);
  const int q0 = (g & 7) * 128;
  const int tid = threadIdx.x, wave = tid >> 6, lane = tid & 63;
  const int lm = lane & 15, lg = lane >> 4, lk8 = lg * 8;
  const int sw = (lm & 7) << 4;                           // K/V read XOR (16B slots)
  const int b = bh >> 3, h = bh & 7;

  const unsigned short* kbh = kb + bh * 131072;
  const unsigned short* vbh = vtb + bh * 131072;

  // Q^T B-fragments for 2 q-subtiles (q pre-scaled by (1/32)*log2e in k_qkv)
  bf16x8 aq[2][4];
#pragma unroll
  for (int qs = 0; qs < 2; qs++) {
    const unsigned short* qrow = qb + (bh * 1024 + q0 + wave * 32 + qs * 16 + lm) * 128;
#pragma unroll
    for (int kc = 0; kc < 4; kc++) aq[qs][kc] = *(const bf16x8*)(qrow + kc * 32 + lk8);
  }

  f32x4 oacc[2][8];                                       // O^T[d=16dt+4lg+j][q=lm]
#pragma unroll
  for (int qs = 0; qs < 2; qs++)
#pragma unroll
    for (int dt = 0; dt < 8; dt++) oacc[qs][dt] = {0.f, 0.f, 0.f, 0.f};
  float mrun[2] = {0.f, 0.f}, lrun[2] = {0.f, 0.f};       // log2 domain

  auto stage = [&](int kt, int buf) {
#pragma unroll
    for (int ii = 0; ii < 4; ii++) {            // K: 64 rows x 256B; wave covers 16 rows
      int krow = wave * 16 + ii * 4 + (lane >> 4);
      int c = (lane & 15) ^ (krow & 7);
      gll16(kbh + (kt * 64 + krow) * 128 + c * 8, &Ks[buf][wave * 16 + ii * 4][0]);
    }
#pragma unroll
    for (int ii = 0; ii < 4; ii++) {            // Vt: 128 rows x 128B; wave covers 32 rows
      int vrow = wave * 32 + ii * 8 + (lane >> 3);
      int c = (lane & 7) ^ (vrow & 7);
      gll16(vbh + vrow * 1024 + kt * 64 + c * 8, &Vts[buf][wave * 32 + ii * 8][0]);
    }
  };

  stage(0, 0);
  __syncthreads();
  int cur = 0;

  for (int kt = 0; kt < 16; kt++) {
    if (kt < 15) stage(kt + 1, cur ^ 1);        // async prefetch into other buffer
    __builtin_amdgcn_sched_barrier(0);          // keep gll issue ahead of compute

#pragma unroll
    for (int h2 = 0; h2 < 2; h2++) {            // two 32-key halves per staged tile
      // S^T = K · Q^T : lane holds S^T[16nt+4lg+j][q=qs*16+lm] (log2 domain)
      f32x4 sc[2][2];
      __builtin_amdgcn_s_setprio(1);
#pragma unroll
      for (int nt = 0; nt < 2; nt++) {
        f32x4 a0 = {0.f, 0.f, 0.f, 0.f}, a1 = {0.f, 0.f, 0.f, 0.f};
        const char* krowp = (const char*)&Ks[cur][h2 * 32 + nt * 16 + lm][0];
#pragma unroll
        for (int kc = 0; kc < 4; kc++) {
          bf16x8 ak = *(const bf16x8*)(krowp + ((kc * 64 + lg * 16) ^ sw));
          a0 = __builtin_amdgcn_mfma_f32_16x16x32_bf16(ak, aq[0][kc], a0, 0, 0, 0);
          a1 = __builtin_amdgcn_mfma_f32_16x16x32_bf16(ak, aq[1][kc], a1, 0, 0, 0);
        }
        sc[0][nt] = a0; sc[1][nt] = a1;
      }
      __builtin_amdgcn_s_setprio(0);

      // online softmax per q-subtile, base-2, defer-max (THR=8); P in registers.
      unsigned int pw[2][2][2];                 // [qs][nt][w], compile-time indices
#pragma unroll
      for (int qs = 0; qs < 2; qs++) {
        float mx8 = fmaxf(fmaxf(fmaxf(sc[qs][0][0], sc[qs][0][1]), fmaxf(sc[qs][0][2], sc[qs][0][3])),
                          fmaxf(fmaxf(sc[qs][1][0], sc[qs][1][1]), fmaxf(sc[qs][1][2], sc[qs][1][3])));
        if (!__all(mx8 <= mrun[qs] + 8.f)) {
          float mx = fmaxf(mx8, __shfl_xor(mx8, 16));
          mx = fmaxf(mx, __shfl_xor(mx, 32));
          float mnew = fmaxf(mrun[qs], mx);
          float corr = __builtin_exp2f(mrun[qs] - mnew);
          mrun[qs] = mnew;
          lrun[qs] *= corr;
#pragma unroll
          for (int dt = 0; dt < 8; dt++)
#pragma unroll
            for (int j = 0; j < 4; j++) oacc[qs][dt][j] *= corr;
        }
        float ts = 0.f;
#pragma unroll
        for (int nt = 0; nt < 2; nt++) {
          float e0 = __builtin_exp2f(sc[qs][nt][0] - mrun[qs]);
          float e1 = __builtin_exp2f(sc[qs][nt][1] - mrun[qs]);
          float e2 = __builtin_exp2f(sc[qs][nt][2] - mrun[qs]);
          float e3 = __builtin_exp2f(sc[qs][nt][3] - mrun[qs]);
          ts += (e0 + e1) + (e2 + e3);
          asm("v_cvt_pk_bf16_f32 %0, %1, %2" : "=v"(pw[qs][nt][0]) : "v"(e0), "v"(e1));
          asm("v_cvt_pk_bf16_f32 %0, %1, %2" : "=v"(pw[qs][nt][1]) : "v"(e2), "v"(e3));
        }
        lrun[qs] += ts;                          // lane-partial; reduced in epilogue
      }

      // PV B-frags: lane (lm,lg) needs P[q][pi(8lg+i)] = its own pw dwords.
      u32x4 t0 = {pw[0][0][0], pw[0][0][1], pw[0][1][0], pw[0][1][1]};
      u32x4 t1 = {pw[1][0][0], pw[1][0][1], pw[1][1][0], pw[1][1][1]};
      bf16x8 pb0 = *(bf16x8*)&t0;
      bf16x8 pb1 = *(bf16x8*)&t1;

      // O^T += V^T · P^T  (V in pi-permuted key order per 32-key subtile)
      __builtin_amdgcn_s_setprio(1);
#pragma unroll
      for (int dt = 0; dt < 8; dt++) {
        bf16x8 av = *(const bf16x8*)((const char*)&Vts[cur][dt * 16 + lm][0] +
                                     ((h2 * 64 + lg * 16) ^ sw));
        oacc[0][dt] = __builtin_amdgcn_mfma_f32_16x16x32_bf16(av, pb0, oacc[0][dt], 0, 0, 0);
        oacc[1][dt] = __builtin_amdgcn_mfma_f32_16x16x32_bf16(av, pb1, oacc[1][dt], 0, 0, 0);
      }
      __builtin_amdgcn_s_setprio(0);
    }

    __syncthreads();            // drains this kt's reads of cur AND gll writes to cur^1
    cur ^= 1;
  }

  // epilogue: reduce l across lane groups, O^T / l -> ob[B,N,H*128]
#pragma unroll
  for (int qs = 0; qs < 2; qs++) {
    float l = lrun[qs];
    l += __shfl_xor(l, 16);
    l += __shfl_xor(l, 32);
    float inv = 1.0f / l;
    unsigned short* orow = ob + ((b * 1024 + q0 + wave * 32 + qs * 16 + lm) * 8 + h) * 128;
#pragma unroll
    for (int dt = 0; dt < 8; dt++) {
#pragma unroll
      for (int pp = 0; pp < 2; pp++) {
        ushort2 o2;
        o2.x = f2bf(oacc[qs][dt][2 * pp]     * inv);
        o2.y = f2bf(oacc[qs][dt][2 * pp + 1] * inv);
        *(ushort2*)&orow[dt * 16 + 4 * lg + 2 * pp] = o2;
      }
    }
  }
}

// ------------- proj GEMM: [16384,1024] @ [1024,128] + bias -> fp32 ----------
// (byte-identical to R11/R13/R14/R18)
__global__ __launch_bounds__(256) void k_proj(const unsigned short* __restrict__ ob,
                                              const unsigned short* __restrict__ wpt, // [128][1024]
                                              const float* __restrict__ bproj,
                                              float* __restrict__ out) {
  __shared__ __align__(16) unsigned short Os[2][64][128];
  __shared__ __align__(16) unsigned short Ws2[2][128][128];
  const int m0 = blockIdx.x * 64;
  const int tid = threadIdx.x, wave = tid >> 6, lane = tid & 63;
  const int lm = lane & 15, lg = lane >> 4;
  const int wr = wave >> 1, wc = wave & 1;

  auto stage = [&](int kt, int buf) {
#pragma unroll
    for (int ii = 0; ii < 4; ii++) {             // O tile: 64 rows x 256B
      int row = wave * 16 + ii * 4 + (lane >> 4);
      int c = (lane & 15) ^ (row & 7);
      gll16(ob + (m0 + row) * 1024 + kt * 128 + c * 8, &Os[buf][wave * 16 + ii * 4][0]);
    }
#pragma unroll
    for (int ii = 0; ii < 8; ii++) {             // W tile: 128 rows x 256B
      int row = wave * 32 + ii * 4 + (lane >> 4);
      int c = (lane & 15) ^ (row & 7);
      gll16(wpt + row * 1024 + kt * 128 + c * 8, &Ws2[buf][wave * 32 + ii * 4][0]);
    }
  };

  f32x4 acc[2][4];
#pragma unroll
  for (int i = 0; i < 2; i++)
#pragma unroll
    for (int j = 0; j < 4; j++) acc[i][j] = {0.f, 0.f, 0.f, 0.f};

  stage(0, 0);
  __syncthreads();
  int cur = 0;

  for (int kt = 0; kt < 8; kt++) {
    if (kt < 7) stage(kt + 1, cur ^ 1);
    __builtin_amdgcn_sched_barrier(0);
#pragma unroll
    for (int k32 = 0; k32 < 4; k32++) {
      bf16x8 af[2], bfr[4];
#pragma unroll
      for (int mi = 0; mi < 2; mi++) {
        int row = wr * 32 + mi * 16 + lm;
        af[mi] = *(const bf16x8*)((const char*)&Os[cur][row][0] + ((k32 * 64 + lg * 16) ^ ((lm & 7) << 4)));
      }
#pragma unroll
      for (int ni = 0; ni < 4; ni++) {
        int row = wc * 64 + ni * 16 + lm;
        bfr[ni] = *(const bf16x8*)((const char*)&Ws2[cur][row][0] + ((k32 * 64 + lg * 16) ^ ((lm & 7) << 4)));
      }
#pragma unroll
      for (int mi = 0; mi < 2; mi++)
#pragma unroll
        for (int ni = 0; ni < 4; ni++)
          acc[mi][ni] = __builtin_amdgcn_mfma_f32_16x16x32_bf16(af[mi], bfr[ni], acc[mi][ni], 0, 0, 0);
    }
    __syncthreads();
    cur ^= 1;
  }

#pragma unroll
  for (int mi = 0; mi < 2; mi++)
#pragma unroll
    for (int ni = 0; ni < 4; ni++)
#pragma unroll
      for (int j = 0; j < 4; j++) {
        int m = m0 + wr * 32 + mi * 16 + 4 * (lane >> 4) + j;
        int n = wc * 64 + ni * 16 + lm;
        out[m * 128 + n] = acc[mi][ni][j] + bproj[n];
      }
}

extern "C" void kernel_launch(void* const* d_in, const int* in_sizes, int n_in,
                              void* d_out, int out_size, void* d_ws, size_t ws_size,
                              hipStream_t stream) {
  const float* x     = (const float*)d_in[0];
  const float* gamma = (const float*)d_in[1];
  const float* beta  = (const float*)d_in[2];
  const float* wqkv  = (const float*)d_in[3];
  const float* wproj = (const float*)d_in[4];
  const float* bproj = (const float*)d_in[5];
  float* out = (float*)d_out;

  unsigned short* ws = (unsigned short*)d_ws;
  unsigned short* xb     = ws;                       // 16384*128      = 2,097,152
  unsigned short* wqkvT  = xb + 2097152;             // 3072*128       =   393,216
  unsigned short* wprojT = wqkvT + 393216;           // 128*1024       =   131,072
  unsigned short* qbuf   = wprojT + 131072;          // 16*8*1024*128  = 16,777,216
  unsigned short* kbuf   = qbuf + 16777216;
  unsigned short* vtbuf  = kbuf + 16777216;
  unsigned short* obuf   = vtbuf + 16777216;         // total ~139.5 MB

  hipLaunchKernelGGL(k_prep, dim3(4152),    dim3(256), 0, stream, x, gamma, beta, wqkv, wproj, xb, wqkvT, wprojT);
  hipLaunchKernelGGL(k_qkv,  dim3(256, 24), dim3(256), 0, stream, xb, wqkvT, qbuf, kbuf, vtbuf);
  hipLaunchKernelGGL(k_flash, dim3(1024),   dim3(256), 0, stream, qbuf, kbuf, vtbuf, obuf);
  hipLaunchKernelGGL(k_proj, dim3(256),     dim3(256), 0, stream, obuf, wprojT, bproj, out);
}